// Round 2
// baseline (1120.427 us; speedup 1.0000x reference)
//
#include <hip/hip_runtime.h>

#define F_IN 128
#define HID 64
#define NCLS 40

// ---------------- CSR build: count in-degree ----------------
__global__ void cnt_kernel(const int* __restrict__ dst, int* __restrict__ cnt, int E) {
    int i = blockIdx.x * blockDim.x + threadIdx.x;
    if (i < E) atomicAdd(&cnt[dst[i]], 1);
}

// ---------------- scan pass A: per-block (1024 elems) inclusive scan ----------------
__global__ __launch_bounds__(256) void scan_a_kernel(
    const int* __restrict__ cnt, int* __restrict__ rowptr,
    int* __restrict__ partials, int N)
{
    __shared__ int sls[256];
    const int t = threadIdx.x;
    const int base = blockIdx.x * 1024 + t * 4;
    int a[4];
    #pragma unroll
    for (int k = 0; k < 4; k++) a[k] = (base + k < N) ? cnt[base + k] : 0;
    // local inclusive
    a[1] += a[0]; a[2] += a[1]; a[3] += a[2];
    sls[t] = a[3];
    __syncthreads();
    for (int off = 1; off < 256; off <<= 1) {
        int v = (t >= off) ? sls[t - off] : 0;
        __syncthreads();
        sls[t] += v;
        __syncthreads();
    }
    const int prefix = sls[t] - a[3];   // exclusive prefix of this thread
    #pragma unroll
    for (int k = 0; k < 4; k++)
        if (base + k < N) rowptr[base + k + 1] = prefix + a[k];
    if (t == 255) partials[blockIdx.x] = sls[255];
}

// ---------------- scan pass B: serial exclusive scan of block totals ----------------
__global__ void scan_b_kernel(int* __restrict__ partials, int* __restrict__ rowptr, int nblocks) {
    if (threadIdx.x == 0 && blockIdx.x == 0) {
        rowptr[0] = 0;
        int run = 0;
        for (int i = 0; i < nblocks; i++) {
            int v = partials[i];
            partials[i] = run;
            run += v;
        }
    }
}

// ---------------- scan pass C: add block offsets ----------------
__global__ __launch_bounds__(256) void scan_c_kernel(
    int* __restrict__ rowptr, const int* __restrict__ partials, int N)
{
    const int base = blockIdx.x * 1024 + threadIdx.x * 4;
    const int off = partials[blockIdx.x];
    #pragma unroll
    for (int k = 0; k < 4; k++)
        if (base + k < N) rowptr[base + k + 1] += off;
}

// ---------------- CSR fill: csr[rowptr[d] + pos] = src ----------------
__global__ void fill_kernel(const int* __restrict__ src, const int* __restrict__ dst,
                            const int* __restrict__ rowptr, int* __restrict__ cursor,
                            int* __restrict__ csr, int E)
{
    int e = blockIdx.x * blockDim.x + threadIdx.x;
    if (e < E) {
        int d = dst[e];
        int pos = atomicAdd(&cursor[d], 1);
        csr[rowptr[d] + pos] = src[e];
    }
}

// ---------------- layer-1 fused GEMM: p1 = x@W1l, q1 = x@W1r + b1 ----------------
__global__ __launch_bounds__(256) void gemm1_kernel(
    const float* __restrict__ x, const float* __restrict__ Wl,
    const float* __restrict__ Wr, const float* __restrict__ b1,
    float* __restrict__ p1, float* __restrict__ q1, int N)
{
    __shared__ float sWl[F_IN * HID];   // 32 KB
    __shared__ float sWr[F_IN * HID];   // 32 KB
    __shared__ float sx[16 * F_IN];     // 8 KB
    const int tid = threadIdx.x;
    for (int idx = tid; idx < F_IN * HID; idx += 256) {
        sWl[idx] = Wl[idx];
        sWr[idx] = Wr[idx];
    }
    const int node0 = blockIdx.x * 16;
    for (int idx = tid; idx < 16 * F_IN; idx += 256) {
        int n = node0 + (idx >> 7);
        sx[idx] = (n < N) ? x[(size_t)node0 * F_IN + idx] : 0.0f;
    }
    __syncthreads();
    const int f = tid & 63;
    const int r0 = tid >> 6;   // 0..3
    float accL[4] = {0.f, 0.f, 0.f, 0.f};
    float accR[4] = {0.f, 0.f, 0.f, 0.f};
    #pragma unroll 8
    for (int k = 0; k < F_IN; k++) {
        float wl = sWl[k * HID + f];
        float wr = sWr[k * HID + f];
        #pragma unroll
        for (int i = 0; i < 4; i++) {
            float xv = sx[(r0 + i * 4) * F_IN + k];
            accL[i] += xv * wl;
            accR[i] += xv * wr;
        }
    }
    const float bb = b1[f];
    #pragma unroll
    for (int i = 0; i < 4; i++) {
        int n = node0 + r0 + i * 4;
        if (n < N) {
            p1[n * HID + f] = accL[i];
            q1[n * HID + f] = accR[i] + bb;
        }
    }
}

// ---------------- layer-1 aggregate (gather) + relu, fused: h = relu(mean + q1) ----------------
// one wave (64 lanes) per node; lane = feature
__global__ __launch_bounds__(256) void agg1_kernel(
    const int* __restrict__ rowptr, const int* __restrict__ csr,
    const float* __restrict__ p1, float* __restrict__ q1 /* in-out -> h */, int N)
{
    const int node = (blockIdx.x * 256 + threadIdx.x) >> 6;
    const int f = threadIdx.x & 63;
    if (node >= N) return;
    const int beg = rowptr[node];
    const int end = rowptr[node + 1];
    float s = 0.f;
    for (int j = beg; j < end; j++) {
        int sidx = csr[j];
        s += p1[(size_t)sidx * HID + f];
    }
    float dg = (float)(end - beg);
    dg = dg > 1.f ? dg : 1.f;
    float v = s / dg + q1[(size_t)node * HID + f];
    q1[(size_t)node * HID + f] = v > 0.f ? v : 0.f;
}

// ---------------- layer-2 GEMM: p2 = h@W2l ----------------
__global__ __launch_bounds__(320) void gemm2_kernel(
    const float* __restrict__ h, const float* __restrict__ W2l,
    float* __restrict__ p2, int N)
{
    __shared__ float sW[HID * NCLS];  // 10 KB
    __shared__ float sh[8 * HID];     // 2 KB
    const int tid = threadIdx.x;
    for (int idx = tid; idx < HID * NCLS; idx += 320) sW[idx] = W2l[idx];
    const int node0 = blockIdx.x * 8;
    for (int idx = tid; idx < 8 * HID; idx += 320) {
        int n = node0 + (idx >> 6);
        sh[idx] = (n < N) ? h[(size_t)node0 * HID + idx] : 0.f;
    }
    __syncthreads();
    const int j = tid % NCLS;
    const int r = tid / NCLS;
    float acc = 0.f;
    #pragma unroll
    for (int k = 0; k < HID; k++) acc += sh[r * HID + k] * sW[k * NCLS + j];
    int n = node0 + r;
    if (n < N) p2[n * NCLS + j] = acc;
}

// ---------------- final: aggregate p2 via CSR + h@W2r + b2, log_softmax ----------------
__global__ __launch_bounds__(320) void final_kernel(
    const float* __restrict__ h, const float* __restrict__ W2r,
    const float* __restrict__ b2, const float* __restrict__ p2,
    const int* __restrict__ rowptr, const int* __restrict__ csr,
    float* __restrict__ out, int N)
{
    __shared__ float sW[HID * NCLS];  // 10 KB
    __shared__ float sh[8 * HID];     // 2 KB
    __shared__ float so[320];
    const int tid = threadIdx.x;
    for (int idx = tid; idx < HID * NCLS; idx += 320) sW[idx] = W2r[idx];
    const int node0 = blockIdx.x * 8;
    for (int idx = tid; idx < 8 * HID; idx += 320) {
        int n = node0 + (idx >> 6);
        sh[idx] = (n < N) ? h[(size_t)node0 * HID + idx] : 0.f;
    }
    __syncthreads();
    const int j = tid % NCLS;
    const int r = tid / NCLS;
    const int n = node0 + r;
    float acc = 0.f;
    #pragma unroll
    for (int k = 0; k < HID; k++) acc += sh[r * HID + k] * sW[k * NCLS + j];
    // CSR aggregation of p2
    int beg = 0, end = 0;
    if (n < N) { beg = rowptr[n]; end = rowptr[n + 1]; }
    float s2 = 0.f;
    for (int jj = beg; jj < end; jj++) {
        int sidx = csr[jj];
        s2 += p2[(size_t)sidx * NCLS + j];
    }
    float dg = (float)(end - beg);
    dg = dg > 1.f ? dg : 1.f;
    float o = acc + b2[j] + s2 / dg;
    so[tid] = o;
    __syncthreads();
    float m = -1e30f;
    #pragma unroll
    for (int k = 0; k < NCLS; k++) m = fmaxf(m, so[r * NCLS + k]);
    float s = 0.f;
    #pragma unroll
    for (int k = 0; k < NCLS; k++) s += __expf(so[r * NCLS + k] - m);
    if (n < N) out[n * NCLS + j] = o - m - __logf(s);
}

extern "C" void kernel_launch(void* const* d_in, const int* in_sizes, int n_in,
                              void* d_out, int out_size, void* d_ws, size_t ws_size,
                              hipStream_t stream) {
    const float* x   = (const float*)d_in[0];
    const int*   ei  = (const int*)d_in[1];
    const float* W1l = (const float*)d_in[2];
    const float* W1r = (const float*)d_in[3];
    const float* b1  = (const float*)d_in[4];
    const float* W2l = (const float*)d_in[5];
    const float* W2r = (const float*)d_in[6];
    const float* b2  = (const float*)d_in[7];

    const int N = in_sizes[0] / F_IN;
    const int E = in_sizes[1] / 2;
    const int* src = ei;
    const int* dst = ei + E;

    // workspace layout (int-element offsets; all 4B)
    int*   wsi     = (int*)d_ws;
    int*   cnt     = wsi;                  // N
    int*   cursor  = wsi + N;              // N
    int*   rowptr  = wsi + 2 * N;          // N+1
    int*   partials= wsi + 3 * N + 4;      // <=256
    int*   csr     = wsi + 3 * N + 260;    // E  (offset mult of 4)
    float* p1      = (float*)(wsi + 3 * N + 260 + E);   // 64N (reused as p2: 40N)
    float* q1      = p1 + (size_t)64 * N;               // 64N (becomes h in-place)
    float* out     = (float*)d_out;

    const int SCAN_BLOCKS = (N + 1023) / 1024;

    // zero cnt + cursor (contiguous 2N ints)
    hipMemsetAsync(cnt, 0, (size_t)2 * N * sizeof(int), stream);

    cnt_kernel<<<(E + 255) / 256, 256, 0, stream>>>(dst, cnt, E);
    scan_a_kernel<<<SCAN_BLOCKS, 256, 0, stream>>>(cnt, rowptr, partials, N);
    scan_b_kernel<<<1, 64, 0, stream>>>(partials, rowptr, SCAN_BLOCKS);
    scan_c_kernel<<<SCAN_BLOCKS, 256, 0, stream>>>(rowptr, partials, N);
    fill_kernel<<<(E + 255) / 256, 256, 0, stream>>>(src, dst, rowptr, cursor, csr, E);

    gemm1_kernel<<<(N + 15) / 16, 256, 0, stream>>>(x, W1l, W1r, b1, p1, q1, N);
    agg1_kernel<<<(N + 3) / 4, 256, 0, stream>>>(rowptr, csr, p1, q1, N);
    gemm2_kernel<<<(N + 7) / 8, 320, 0, stream>>>(q1, W2l, p1 /* p2 */, N);
    final_kernel<<<(N + 7) / 8, 320, 0, stream>>>(q1, W2r, b2, p1 /* p2 */,
                                                  rowptr, csr, out, N);
}

// Round 3
// 503.372 us; speedup vs baseline: 2.2258x; 2.2258x over previous
//
#include <hip/hip_runtime.h>

#define F_IN 128
#define HID 64
#define NCLS 40

// ---------------- CSR build: count in-degree ----------------
__global__ void cnt_kernel(const int* __restrict__ dst, int* __restrict__ cnt, int E) {
    int i = blockIdx.x * blockDim.x + threadIdx.x;
    if (i < E) atomicAdd(&cnt[dst[i]], 1);
}

// ---------------- scan pass A ----------------
__global__ __launch_bounds__(256) void scan_a_kernel(
    const int* __restrict__ cnt, int* __restrict__ rowptr,
    int* __restrict__ partials, int N)
{
    __shared__ int sls[256];
    const int t = threadIdx.x;
    const int base = blockIdx.x * 1024 + t * 4;
    int a[4];
    #pragma unroll
    for (int k = 0; k < 4; k++) a[k] = (base + k < N) ? cnt[base + k] : 0;
    a[1] += a[0]; a[2] += a[1]; a[3] += a[2];
    sls[t] = a[3];
    __syncthreads();
    for (int off = 1; off < 256; off <<= 1) {
        int v = (t >= off) ? sls[t - off] : 0;
        __syncthreads();
        sls[t] += v;
        __syncthreads();
    }
    const int prefix = sls[t] - a[3];
    #pragma unroll
    for (int k = 0; k < 4; k++)
        if (base + k < N) rowptr[base + k + 1] = prefix + a[k];
    if (t == 255) partials[blockIdx.x] = sls[255];
}

// ---------------- scan pass B ----------------
__global__ void scan_b_kernel(int* __restrict__ partials, int* __restrict__ rowptr, int nblocks) {
    if (threadIdx.x == 0 && blockIdx.x == 0) {
        rowptr[0] = 0;
        int run = 0;
        for (int i = 0; i < nblocks; i++) {
            int v = partials[i];
            partials[i] = run;
            run += v;
        }
    }
}

// ---------------- scan pass C ----------------
__global__ __launch_bounds__(256) void scan_c_kernel(
    int* __restrict__ rowptr, const int* __restrict__ partials, int N)
{
    const int base = blockIdx.x * 1024 + threadIdx.x * 4;
    const int off = partials[blockIdx.x];
    #pragma unroll
    for (int k = 0; k < 4; k++)
        if (base + k < N) rowptr[base + k + 1] += off;
}

// ---------------- CSR fill ----------------
__global__ void fill_kernel(const int* __restrict__ src, const int* __restrict__ dst,
                            const int* __restrict__ rowptr, int* __restrict__ cursor,
                            int* __restrict__ csr, int E)
{
    int e = blockIdx.x * blockDim.x + threadIdx.x;
    if (e < E) {
        int d = dst[e];
        int pos = atomicAdd(&cursor[d], 1);
        csr[rowptr[d] + pos] = src[e];
    }
}

// ---------------- layer-1 fused GEMM: p1 = x@W1l, q1 = x@W1r + b1 ----------------
__global__ __launch_bounds__(256) void gemm1_kernel(
    const float* __restrict__ x, const float* __restrict__ Wl,
    const float* __restrict__ Wr, const float* __restrict__ b1,
    float* __restrict__ p1, float* __restrict__ q1, int N)
{
    __shared__ float sWl[F_IN * HID];
    __shared__ float sWr[F_IN * HID];
    __shared__ float sx[16 * F_IN];
    const int tid = threadIdx.x;
    for (int idx = tid; idx < F_IN * HID; idx += 256) {
        sWl[idx] = Wl[idx];
        sWr[idx] = Wr[idx];
    }
    const int node0 = blockIdx.x * 16;
    for (int idx = tid; idx < 16 * F_IN; idx += 256) {
        int n = node0 + (idx >> 7);
        sx[idx] = (n < N) ? x[(size_t)node0 * F_IN + idx] : 0.0f;
    }
    __syncthreads();
    const int f = tid & 63;
    const int r0 = tid >> 6;
    float accL[4] = {0.f, 0.f, 0.f, 0.f};
    float accR[4] = {0.f, 0.f, 0.f, 0.f};
    #pragma unroll 8
    for (int k = 0; k < F_IN; k++) {
        float wl = sWl[k * HID + f];
        float wr = sWr[k * HID + f];
        #pragma unroll
        for (int i = 0; i < 4; i++) {
            float xv = sx[(r0 + i * 4) * F_IN + k];
            accL[i] += xv * wl;
            accR[i] += xv * wr;
        }
    }
    const float bb = b1[f];
    #pragma unroll
    for (int i = 0; i < 4; i++) {
        int n = node0 + r0 + i * 4;
        if (n < N) {
            p1[n * HID + f] = accL[i];
            q1[n * HID + f] = accR[i] + bb;
        }
    }
}

// ---------------- layer-1 aggregate + relu: h = relu(mean(p1[nbrs]) + q1), in-place on q1 ----------------
__global__ __launch_bounds__(256) void agg1_kernel(
    const int* __restrict__ rowptr, const int* __restrict__ csr,
    const float* __restrict__ p1, float* __restrict__ q1, int N)
{
    const int node = (blockIdx.x * 256 + threadIdx.x) >> 6;
    const int f = threadIdx.x & 63;
    if (node >= N) return;
    const int beg = rowptr[node];
    const int end = rowptr[node + 1];
    float s0 = 0.f, s1 = 0.f, s2 = 0.f, s3 = 0.f;
    int j = beg;
    for (; j + 3 < end; j += 4) {
        int a = csr[j], b = csr[j + 1], c = csr[j + 2], d = csr[j + 3];
        s0 += p1[(size_t)a * HID + f];
        s1 += p1[(size_t)b * HID + f];
        s2 += p1[(size_t)c * HID + f];
        s3 += p1[(size_t)d * HID + f];
    }
    for (; j < end; j++) s0 += p1[(size_t)csr[j] * HID + f];
    float s = (s0 + s1) + (s2 + s3);
    float dg = (float)(end - beg);
    dg = dg > 1.f ? dg : 1.f;
    float v = s / dg + q1[(size_t)node * HID + f];
    q1[(size_t)node * HID + f] = v > 0.f ? v : 0.f;
}

// ---------------- layer-2 aggregate: aggh = mean(h[nbrs]) ----------------
__global__ __launch_bounds__(256) void agg2_kernel(
    const int* __restrict__ rowptr, const int* __restrict__ csr,
    const float* __restrict__ h, float* __restrict__ aggh, int N)
{
    const int node = (blockIdx.x * 256 + threadIdx.x) >> 6;
    const int f = threadIdx.x & 63;
    if (node >= N) return;
    const int beg = rowptr[node];
    const int end = rowptr[node + 1];
    float s0 = 0.f, s1 = 0.f, s2 = 0.f, s3 = 0.f;
    int j = beg;
    for (; j + 3 < end; j += 4) {
        int a = csr[j], b = csr[j + 1], c = csr[j + 2], d = csr[j + 3];
        s0 += h[(size_t)a * HID + f];
        s1 += h[(size_t)b * HID + f];
        s2 += h[(size_t)c * HID + f];
        s3 += h[(size_t)d * HID + f];
    }
    for (; j < end; j++) s0 += h[(size_t)csr[j] * HID + f];
    float s = (s0 + s1) + (s2 + s3);
    float dg = (float)(end - beg);
    dg = dg > 1.f ? dg : 1.f;
    aggh[(size_t)node * HID + f] = s / dg;
}

// ---------------- final dense: out = log_softmax(aggh@W2l + h@W2r + b2) ----------------
#define FN_NODES 64
__global__ __launch_bounds__(256) void final_kernel(
    const float* __restrict__ h, const float* __restrict__ aggh,
    const float* __restrict__ W2l, const float* __restrict__ W2r,
    const float* __restrict__ b2, float* __restrict__ out, int N)
{
    __shared__ float sWl[HID * NCLS];       // 10 KB
    __shared__ float sWr[HID * NCLS];       // 10 KB
    __shared__ float sh[FN_NODES * 65];     // 16.25 KB (pad 65 -> conflict-free)
    __shared__ float sa[FN_NODES * 65];     // 16.25 KB
    const int tid = threadIdx.x;
    for (int i = tid; i < HID * NCLS; i += 256) { sWl[i] = W2l[i]; sWr[i] = W2r[i]; }
    const int node0 = blockIdx.x * FN_NODES;
    for (int i = tid; i < FN_NODES * HID; i += 256) {
        int r = i >> 6, c = i & 63;
        int n = node0 + r;
        sh[r * 65 + c] = (n < N) ? h[(size_t)n * HID + c] : 0.f;
        sa[r * 65 + c] = (n < N) ? aggh[(size_t)n * HID + c] : 0.f;
    }
    __syncthreads();
    const int r = tid >> 2;       // node within block
    const int g = tid & 3;        // class group: 10 classes each
    const int n = node0 + r;
    float acc[10];
    #pragma unroll
    for (int i = 0; i < 10; i++) acc[i] = 0.f;
    const float* shr = &sh[r * 65];
    const float* sar = &sa[r * 65];
    #pragma unroll 4
    for (int k = 0; k < HID; k++) {
        float hv = shr[k], av = sar[k];
        #pragma unroll
        for (int i = 0; i < 10; i++) {
            int j = g * 10 + i;
            acc[i] += av * sWl[k * NCLS + j] + hv * sWr[k * NCLS + j];
        }
    }
    float m = -1e30f;
    #pragma unroll
    for (int i = 0; i < 10; i++) { acc[i] += b2[g * 10 + i]; m = fmaxf(m, acc[i]); }
    m = fmaxf(m, __shfl_xor(m, 1, 4));
    m = fmaxf(m, __shfl_xor(m, 2, 4));
    float s = 0.f;
    #pragma unroll
    for (int i = 0; i < 10; i++) s += __expf(acc[i] - m);
    s += __shfl_xor(s, 1, 4);
    s += __shfl_xor(s, 2, 4);
    const float lse = m + __logf(s);
    if (n < N) {
        #pragma unroll
        for (int i = 0; i < 10; i++)
            out[(size_t)n * NCLS + g * 10 + i] = acc[i] - lse;
    }
}

extern "C" void kernel_launch(void* const* d_in, const int* in_sizes, int n_in,
                              void* d_out, int out_size, void* d_ws, size_t ws_size,
                              hipStream_t stream) {
    const float* x   = (const float*)d_in[0];
    const int*   ei  = (const int*)d_in[1];
    const float* W1l = (const float*)d_in[2];
    const float* W1r = (const float*)d_in[3];
    const float* b1  = (const float*)d_in[4];
    const float* W2l = (const float*)d_in[5];
    const float* W2r = (const float*)d_in[6];
    const float* b2  = (const float*)d_in[7];

    const int N = in_sizes[0] / F_IN;
    const int E = in_sizes[1] / 2;
    const int* src = ei;
    const int* dst = ei + E;

    int*   wsi      = (int*)d_ws;
    int*   cnt      = wsi;                  // N
    int*   cursor   = wsi + N;              // N
    int*   rowptr   = wsi + 2 * N;          // N+1
    int*   partials = wsi + 3 * N + 4;      // <=256
    int*   csr      = wsi + 3 * N + 260;    // E
    size_t int_end  = (size_t)3 * N + 260 + E;
    size_t falign   = (int_end + 63) & ~(size_t)63;   // 256B-align float region
    float* p1       = (float*)(wsi + falign);          // 64N  (p1; later aggh)
    float* q1       = p1 + (size_t)64 * N;             // 64N  (q1 -> h in-place)
    float* out      = (float*)d_out;

    const int SCAN_BLOCKS = (N + 1023) / 1024;

    hipMemsetAsync(cnt, 0, (size_t)2 * N * sizeof(int), stream);

    cnt_kernel<<<(E + 255) / 256, 256, 0, stream>>>(dst, cnt, E);
    scan_a_kernel<<<SCAN_BLOCKS, 256, 0, stream>>>(cnt, rowptr, partials, N);
    scan_b_kernel<<<1, 64, 0, stream>>>(partials, rowptr, SCAN_BLOCKS);
    scan_c_kernel<<<SCAN_BLOCKS, 256, 0, stream>>>(rowptr, partials, N);
    fill_kernel<<<(E + 255) / 256, 256, 0, stream>>>(src, dst, rowptr, cursor, csr, E);

    gemm1_kernel<<<(N + 15) / 16, 256, 0, stream>>>(x, W1l, W1r, b1, p1, q1, N);
    agg1_kernel<<<(N + 3) / 4, 256, 0, stream>>>(rowptr, csr, p1, q1, N);
    agg2_kernel<<<(N + 3) / 4, 256, 0, stream>>>(rowptr, csr, q1, p1 /* aggh */, N);
    final_kernel<<<(N + FN_NODES - 1) / FN_NODES, 256, 0, stream>>>(
        q1 /* h */, p1 /* aggh */, W2l, W2r, b2, out, N);
}

// Round 5
// 394.181 us; speedup vs baseline: 2.8424x; 1.2770x over previous
//
#include <hip/hip_runtime.h>

#define F_IN 128
#define HID 64
#define NCLS 40

typedef __attribute__((ext_vector_type(8))) short bf16x8;
typedef __attribute__((ext_vector_type(4))) float f32x4;
typedef __attribute__((ext_vector_type(4))) int int4v;

__device__ __forceinline__ unsigned short f2b(float f) {
    union { float f; unsigned int u; } v; v.f = f;
    unsigned int u = v.u + 0x7FFFu + ((v.u >> 16) & 1u);
    return (unsigned short)(u >> 16);
}
__device__ __forceinline__ float b2f(unsigned short b) {
    union { unsigned int u; float f; } v; v.u = ((unsigned int)b) << 16;
    return v.f;
}

// ---------------- CSR build: count in-degree ----------------
__global__ void cnt_kernel(const int* __restrict__ dst, int* __restrict__ cnt, int E) {
    int i = blockIdx.x * blockDim.x + threadIdx.x;
    if (i < E) atomicAdd(&cnt[dst[i]], 1);
}

// ---------------- scan pass A ----------------
__global__ __launch_bounds__(256) void scan_a_kernel(
    const int* __restrict__ cnt, int* __restrict__ rowptr,
    int* __restrict__ partials, int N)
{
    __shared__ int sls[256];
    const int t = threadIdx.x;
    const int base = blockIdx.x * 1024 + t * 4;
    int a[4];
    #pragma unroll
    for (int k = 0; k < 4; k++) a[k] = (base + k < N) ? cnt[base + k] : 0;
    a[1] += a[0]; a[2] += a[1]; a[3] += a[2];
    sls[t] = a[3];
    __syncthreads();
    for (int off = 1; off < 256; off <<= 1) {
        int v = (t >= off) ? sls[t - off] : 0;
        __syncthreads();
        sls[t] += v;
        __syncthreads();
    }
    const int prefix = sls[t] - a[3];
    #pragma unroll
    for (int k = 0; k < 4; k++)
        if (base + k < N) rowptr[base + k + 1] = prefix + a[k];
    if (t == 255) partials[blockIdx.x] = sls[255];
}

// ---------------- scan pass B ----------------
__global__ void scan_b_kernel(int* __restrict__ partials, int* __restrict__ rowptr, int nblocks) {
    if (threadIdx.x == 0 && blockIdx.x == 0) {
        rowptr[0] = 0;
        int run = 0;
        for (int i = 0; i < nblocks; i++) {
            int v = partials[i];
            partials[i] = run;
            run += v;
        }
    }
}

// ---------------- scan pass C ----------------
__global__ __launch_bounds__(256) void scan_c_kernel(
    int* __restrict__ rowptr, const int* __restrict__ partials, int N)
{
    const int base = blockIdx.x * 1024 + threadIdx.x * 4;
    const int off = partials[blockIdx.x];
    #pragma unroll
    for (int k = 0; k < 4; k++)
        if (base + k < N) rowptr[base + k + 1] += off;
}

// ---------------- CSR fill ----------------
__global__ void fill_kernel(const int* __restrict__ src, const int* __restrict__ dst,
                            const int* __restrict__ rowptr, int* __restrict__ cursor,
                            int* __restrict__ csr, int E)
{
    int e = blockIdx.x * blockDim.x + threadIdx.x;
    if (e < E) {
        int d = dst[e];
        int pos = atomicAdd(&cursor[d], 1);
        csr[rowptr[d] + pos] = src[e];
    }
}

// ---------------- W prep: Wt[col][k] bf16, col 0-63 = W1l, 64-127 = W1r ----------------
__global__ __launch_bounds__(256) void wprep_kernel(
    const float* __restrict__ W1l, const float* __restrict__ W1r,
    unsigned short* __restrict__ Wt)
{
    const int tid = threadIdx.x;
    for (int i = 0; i < 64; i++) {
        int idx = i * 256 + tid;            // 0 .. 16383
        int k = idx >> 7;                   // 0..127
        int c = idx & 127;                  // 0..127
        float v = (c < 64) ? W1l[k * 64 + c] : W1r[k * 64 + (c - 64)];
        Wt[c * 128 + k] = f2b(v);
    }
}

// ---------------- layer-1 MFMA GEMM: p1b(bf16) = x@W1l, q1 = x@W1r + b1 ----------------
// block: 64 nodes x 128 cols, 4 waves (wave = 16 nodes x 128 cols)
__global__ __launch_bounds__(256) void gemm1_kernel(
    const float* __restrict__ x, const unsigned short* __restrict__ Wt,
    const float* __restrict__ b1,
    unsigned short* __restrict__ p1b, float* __restrict__ q1, int N)
{
    __shared__ alignas(16) unsigned short sW[128 * 136];   // 34816 B, padded rows
    const int tid = threadIdx.x;

    // stage Wt (linear global, 16B chunks) -> padded LDS rows
    {
        const int4v* Wg = (const int4v*)Wt;
        #pragma unroll
        for (int i = 0; i < 8; i++) {
            int idx16 = i * 256 + tid;            // 0..2047, 8 ushorts each
            int c = idx16 >> 4;                   // col 0..127
            int k8 = idx16 & 15;                  // which 8-k group
            int4v v = Wg[idx16];
            *(int4v*)&sW[c * 136 + k8 * 8] = v;
        }
    }
    __syncthreads();

    const int w = tid >> 6;        // wave 0..3
    const int lane = tid & 63;
    const int m = lane & 15;       // A-row / B-col / D-col index
    const int g = lane >> 4;       // k-group / D-row group

    const int node0 = blockIdx.x * 64;
    int arow = node0 + w * 16 + m;
    int arow_c = arow < N ? arow : 0;     // clamp for safe load, masked at store
    const float* xr = x + (size_t)arow_c * F_IN;

    f32x4 acc[8];
    #pragma unroll
    for (int c = 0; c < 8; c++) acc[c] = (f32x4){0.f, 0.f, 0.f, 0.f};

    #pragma unroll
    for (int ks = 0; ks < 4; ks++) {
        const int k0 = ks * 32 + g * 8;
        f32x4 xa = *(const f32x4*)(xr + k0);
        f32x4 xb = *(const f32x4*)(xr + k0 + 4);
        bf16x8 a;
        a[0] = (short)f2b(xa.x); a[1] = (short)f2b(xa.y);
        a[2] = (short)f2b(xa.z); a[3] = (short)f2b(xa.w);
        a[4] = (short)f2b(xb.x); a[5] = (short)f2b(xb.y);
        a[6] = (short)f2b(xb.z); a[7] = (short)f2b(xb.w);
        #pragma unroll
        for (int ct = 0; ct < 8; ct++) {
            bf16x8 b = *(const bf16x8*)&sW[(ct * 16 + m) * 136 + k0];
            acc[ct] = __builtin_amdgcn_mfma_f32_16x16x32_bf16(a, b, acc[ct], 0, 0, 0);
        }
    }

    // biases for the q1 half (cols 64..127); b1 is small, L2-resident
    float bias[4];
    #pragma unroll
    for (int ct = 4; ct < 8; ct++) bias[ct - 4] = b1[(ct - 4) * 16 + m];

    #pragma unroll
    for (int ct = 0; ct < 8; ct++) {
        const int col = ct * 16 + m;
        #pragma unroll
        for (int r = 0; r < 4; r++) {
            int nd = node0 + w * 16 + g * 4 + r;
            if (nd < N) {
                if (col < 64)
                    p1b[(size_t)nd * HID + col] = f2b(acc[ct][r]);
                else
                    q1[(size_t)nd * HID + (col - 64)] = acc[ct][r] + bias[ct - 4];
            }
        }
    }
}

// ---------------- layer-1 aggregate + relu: hb = bf16(relu(mean(p1b[nbrs]) + q1)) ----------------
__global__ __launch_bounds__(256) void agg1_kernel(
    const int* __restrict__ rowptr, const int* __restrict__ csr,
    const unsigned short* __restrict__ p1b, const float* __restrict__ q1,
    unsigned short* __restrict__ hb, int N)
{
    const int node = (blockIdx.x * 256 + threadIdx.x) >> 6;
    const int f = threadIdx.x & 63;
    if (node >= N) return;
    const int beg = rowptr[node];
    const int end = rowptr[node + 1];
    float s0 = 0.f, s1 = 0.f, s2 = 0.f, s3 = 0.f;
    float s4 = 0.f, s5 = 0.f, s6 = 0.f, s7 = 0.f;
    int j = beg;
    for (; j + 7 < end; j += 8) {
        int i0 = csr[j], i1 = csr[j+1], i2 = csr[j+2], i3 = csr[j+3];
        int i4 = csr[j+4], i5 = csr[j+5], i6 = csr[j+6], i7 = csr[j+7];
        s0 += b2f(p1b[(size_t)i0 * HID + f]);
        s1 += b2f(p1b[(size_t)i1 * HID + f]);
        s2 += b2f(p1b[(size_t)i2 * HID + f]);
        s3 += b2f(p1b[(size_t)i3 * HID + f]);
        s4 += b2f(p1b[(size_t)i4 * HID + f]);
        s5 += b2f(p1b[(size_t)i5 * HID + f]);
        s6 += b2f(p1b[(size_t)i6 * HID + f]);
        s7 += b2f(p1b[(size_t)i7 * HID + f]);
    }
    for (; j < end; j++) s0 += b2f(p1b[(size_t)csr[j] * HID + f]);
    float s = ((s0 + s1) + (s2 + s3)) + ((s4 + s5) + (s6 + s7));
    float dg = (float)(end - beg);
    dg = dg > 1.f ? dg : 1.f;
    float v = s / dg + q1[(size_t)node * HID + f];
    v = v > 0.f ? v : 0.f;
    hb[(size_t)node * HID + f] = f2b(v);
}

// ---------------- layer-2 aggregate: aggh = mean(hb[nbrs]) (f32 out) ----------------
__global__ __launch_bounds__(256) void agg2_kernel(
    const int* __restrict__ rowptr, const int* __restrict__ csr,
    const unsigned short* __restrict__ hb, float* __restrict__ aggh, int N)
{
    const int node = (blockIdx.x * 256 + threadIdx.x) >> 6;
    const int f = threadIdx.x & 63;
    if (node >= N) return;
    const int beg = rowptr[node];
    const int end = rowptr[node + 1];
    float s0 = 0.f, s1 = 0.f, s2 = 0.f, s3 = 0.f;
    float s4 = 0.f, s5 = 0.f, s6 = 0.f, s7 = 0.f;
    int j = beg;
    for (; j + 7 < end; j += 8) {
        int i0 = csr[j], i1 = csr[j+1], i2 = csr[j+2], i3 = csr[j+3];
        int i4 = csr[j+4], i5 = csr[j+5], i6 = csr[j+6], i7 = csr[j+7];
        s0 += b2f(hb[(size_t)i0 * HID + f]);
        s1 += b2f(hb[(size_t)i1 * HID + f]);
        s2 += b2f(hb[(size_t)i2 * HID + f]);
        s3 += b2f(hb[(size_t)i3 * HID + f]);
        s4 += b2f(hb[(size_t)i4 * HID + f]);
        s5 += b2f(hb[(size_t)i5 * HID + f]);
        s6 += b2f(hb[(size_t)i6 * HID + f]);
        s7 += b2f(hb[(size_t)i7 * HID + f]);
    }
    for (; j < end; j++) s0 += b2f(hb[(size_t)csr[j] * HID + f]);
    float s = ((s0 + s1) + (s2 + s3)) + ((s4 + s5) + (s6 + s7));
    float dg = (float)(end - beg);
    dg = dg > 1.f ? dg : 1.f;
    aggh[(size_t)node * HID + f] = s / dg;
}

// ---------------- final dense: out = log_softmax(aggh@W2l + h@W2r + b2) ----------------
#define FN_NODES 64
__global__ __launch_bounds__(256) void final_kernel(
    const unsigned short* __restrict__ hb, const float* __restrict__ aggh,
    const float* __restrict__ W2l, const float* __restrict__ W2r,
    const float* __restrict__ b2, float* __restrict__ out, int N)
{
    __shared__ float sWl[HID * NCLS];
    __shared__ float sWr[HID * NCLS];
    __shared__ float sh[FN_NODES * 65];
    __shared__ float sa[FN_NODES * 65];
    const int tid = threadIdx.x;
    for (int i = tid; i < HID * NCLS; i += 256) { sWl[i] = W2l[i]; sWr[i] = W2r[i]; }
    const int node0 = blockIdx.x * FN_NODES;
    for (int i = tid; i < FN_NODES * HID; i += 256) {
        int r = i >> 6, c = i & 63;
        int n = node0 + r;
        sh[r * 65 + c] = (n < N) ? b2f(hb[(size_t)n * HID + c]) : 0.f;
        sa[r * 65 + c] = (n < N) ? aggh[(size_t)n * HID + c] : 0.f;
    }
    __syncthreads();
    const int r = tid >> 2;
    const int g = tid & 3;
    const int n = node0 + r;
    float acc[10];
    #pragma unroll
    for (int i = 0; i < 10; i++) acc[i] = 0.f;
    const float* shr = &sh[r * 65];
    const float* sar = &sa[r * 65];
    #pragma unroll 4
    for (int k = 0; k < HID; k++) {
        float hv = shr[k], av = sar[k];
        #pragma unroll
        for (int i = 0; i < 10; i++) {
            int j = g * 10 + i;
            acc[i] += av * sWl[k * NCLS + j] + hv * sWr[k * NCLS + j];
        }
    }
    float m = -1e30f;
    #pragma unroll
    for (int i = 0; i < 10; i++) { acc[i] += b2[g * 10 + i]; m = fmaxf(m, acc[i]); }
    m = fmaxf(m, __shfl_xor(m, 1, 4));
    m = fmaxf(m, __shfl_xor(m, 2, 4));
    float s = 0.f;
    #pragma unroll
    for (int i = 0; i < 10; i++) s += __expf(acc[i] - m);
    s += __shfl_xor(s, 1, 4);
    s += __shfl_xor(s, 2, 4);
    const float lse = m + __logf(s);
    if (n < N) {
        #pragma unroll
        for (int i = 0; i < 10; i++)
            out[(size_t)n * NCLS + g * 10 + i] = acc[i] - lse;
    }
}

extern "C" void kernel_launch(void* const* d_in, const int* in_sizes, int n_in,
                              void* d_out, int out_size, void* d_ws, size_t ws_size,
                              hipStream_t stream) {
    const float* x   = (const float*)d_in[0];
    const int*   ei  = (const int*)d_in[1];
    const float* W1l = (const float*)d_in[2];
    const float* W1r = (const float*)d_in[3];
    const float* b1  = (const float*)d_in[4];
    const float* W2l = (const float*)d_in[5];
    const float* W2r = (const float*)d_in[6];
    const float* b2  = (const float*)d_in[7];

    const int N = in_sizes[0] / F_IN;
    const int E = in_sizes[1] / 2;
    const int* src = ei;
    const int* dst = ei + E;

    // ---- workspace layout (int-element offsets; all 4B) ----
    int*   wsi      = (int*)d_ws;
    int*   cnt      = wsi;                  // N
    int*   cursor   = wsi + N;              // N
    int*   rowptr   = wsi + 2 * N;          // N+1
    int*   partials = wsi + 3 * N + 4;      // <=256
    int*   csr      = wsi + 3 * N + 260;    // E
    size_t o        = ((size_t)3 * N + 260 + E + 63) & ~(size_t)63;  // 256B-align
    unsigned short* Wt  = (unsigned short*)(wsi + o);  o += 8192;      // 16384 ushorts = 32 KB (!!)
    unsigned short* p1b = (unsigned short*)(wsi + o);  o += (size_t)32 * N;  // 64N ushorts
    unsigned short* hb  = (unsigned short*)(wsi + o);  o += (size_t)32 * N;  // 64N ushorts
    float* q1       = (float*)(wsi + o);               // 64N floats (q1; reused as aggh)
    float* aggh     = q1;
    float* out      = (float*)d_out;

    const int SCAN_BLOCKS = (N + 1023) / 1024;

    hipMemsetAsync(cnt, 0, (size_t)2 * N * sizeof(int), stream);

    cnt_kernel<<<(E + 255) / 256, 256, 0, stream>>>(dst, cnt, E);
    scan_a_kernel<<<SCAN_BLOCKS, 256, 0, stream>>>(cnt, rowptr, partials, N);
    scan_b_kernel<<<1, 64, 0, stream>>>(partials, rowptr, SCAN_BLOCKS);
    scan_c_kernel<<<SCAN_BLOCKS, 256, 0, stream>>>(rowptr, partials, N);
    fill_kernel<<<(E + 255) / 256, 256, 0, stream>>>(src, dst, rowptr, cursor, csr, E);

    wprep_kernel<<<1, 256, 0, stream>>>(W1l, W1r, Wt);
    gemm1_kernel<<<(N + 63) / 64, 256, 0, stream>>>(x, Wt, b1, p1b, q1, N);
    agg1_kernel<<<(N + 3) / 4, 256, 0, stream>>>(rowptr, csr, p1b, q1, hb, N);
    agg2_kernel<<<(N + 3) / 4, 256, 0, stream>>>(rowptr, csr, hb, aggh, N);
    final_kernel<<<(N + FN_NODES - 1) / FN_NODES, 256, 0, stream>>>(
        hb, aggh, W2l, W2r, b2, out, N);
}